// Round 3
// baseline (627.908 us; speedup 1.0000x reference)
//
#include <hip/hip_runtime.h>

#define TT 512

typedef __attribute__((ext_vector_type(8))) short bf16x8;
typedef __attribute__((ext_vector_type(4))) float f32x4;
typedef __attribute__((ext_vector_type(4))) int   i32x4;

__device__ inline short f2bf(float f) {
    // round-to-nearest-even fp32 -> bf16
    unsigned u = __float_as_uint(f);
    u += 0x7FFFu + ((u >> 16) & 1u);
    return (short)(u >> 16);
}
__device__ inline float sigm(float x)  { return __fdividef(1.0f, 1.0f + __expf(-x)); }
__device__ inline float tanh_(float x) { return 1.0f - __fdividef(2.0f, 1.0f + __expf(2.0f * x)); }

__device__ inline float bperm(int addr, float v) {
    return __int_as_float(__builtin_amdgcn_ds_bpermute(addr, __float_as_int(v)));
}
// redistribute one C tile: dest lane l gets reg 'grow' from lane l&15
__device__ inline float sel4bp(int addr, const f32x4& c, int grow) {
    float b0 = bperm(addr, c[0]);
    float b1 = bperm(addr, c[1]);
    float b2 = bperm(addr, c[2]);
    float b3 = bperm(addr, c[3]);
    float r01 = (grow & 1) ? b1 : b0;   // masks hoisted (grow loop-invariant)
    float r23 = (grow & 1) ? b3 : b2;
    return (grow & 2) ? r23 : r01;
}
// pack two fp32 -> two bf16 (round-to-nearest, ties-away: +0x8000 before trunc)
__device__ inline int packbf(float f0, float f1) {
    unsigned a = __float_as_uint(f0) + 0x8000u;
    unsigned b = __float_as_uint(f1) + 0x8000u;
    return (int)((a >> 16) | (b & 0xFFFF0000u));
}
__device__ inline bf16x8 packx(const f32x4& a, const f32x4& b) {
    union { i32x4 i; bf16x8 h; } u;
    u.i[0] = packbf(a[0], a[1]);
    u.i[1] = packbf(a[2], a[3]);
    u.i[2] = packbf(b[0], b[1]);
    u.i[3] = packbf(b[2], b[3]);
    return u.h;
}

#define MFMA(A, B, C) __builtin_amdgcn_mfma_f32_16x16x32_bf16((A), (B), (C), 0, 0, 0)

// 768 threads = 12 waves = 3 layers x 4 unit-quarters. WG owns 4 batch rows,
// grid = 256 = 1 WG/CU. Layer pipeline skewed by 2 (wave L does t = s-2L) so
// the producer's h is 2 barriers old -> inp A-frags PREFETCHED one step early.
// Only the own-h read (the recurrence itself) is post-barrier. Preact
// redistribution via ds_bpermute (no LDS round-trip). One barrier per step.
__global__ __launch_bounds__(768, 1)
void gru_fused(const float* __restrict__ x,
               const float* __restrict__ Wih0, const float* __restrict__ Whh0,
               const float* __restrict__ bih0, const float* __restrict__ bhh0,
               const float* __restrict__ Wih1, const float* __restrict__ Whh1,
               const float* __restrict__ bih1, const float* __restrict__ bhh1,
               const float* __restrict__ Wih2, const float* __restrict__ Whh2,
               const float* __restrict__ bih2, const float* __restrict__ bhh2,
               const float* __restrict__ fc1w, const float* __restrict__ fc1b,
               const float* __restrict__ fc2w, const float* __restrict__ fc2b,
               float* __restrict__ out)
{
    // h ring buffers: [layer][t%3][row 0..3][96 shorts] (stride 96 -> 2-way banks, free)
    __shared__ __align__(16) short hbuf[3][3][4 * 96];
    __shared__ float h2out[4][64];
    __shared__ float fcz[4][32];

    const int tid = threadIdx.x;
    const int l   = tid & 63;
    const int wid = tid >> 6;   // 0..11
    const int L   = wid >> 2;   // layer 0..2
    const int qt  = wid & 3;    // unit quarter
    const int n_  = l & 15;     // A row / B col / C col
    const int q   = l >> 4;     // quad
    const int rbase = blockIdx.x * 4;
    const int grow = l >> 4;    // gate: batch row
    const int gcol = l & 15;    // gate: col within quarter
    const int u    = qt * 16 + gcol;
    const int bpa  = (l & 15) * 4;  // bpermute addr

    for (int i = tid; i < 3 * 3 * 4 * 96; i += 768) (&hbuf[0][0][0])[i] = 0;

    const float* Wih = (L == 0) ? Wih0 : (L == 1) ? Wih1 : Wih2;
    const float* Whh = (L == 0) ? Whh0 : (L == 1) ? Whh1 : Whh2;
    const float* bih = (L == 0) ? bih0 : (L == 1) ? bih1 : bih2;
    const float* bhh = (L == 0) ? bhh0 : (L == 1) ? bhh1 : bhh2;
    const int ldih = (L == 0) ? 16 : 64;

    // resident B-frags (gate g: 0=r,1=z,2=n; cols g*64+qt*16..+15; k=kt*32+q*8+j)
    bf16x8 wihf[3][2], whhf[3][2];
#pragma unroll
    for (int g = 0; g < 3; ++g) {
        const int gc = g * 64 + qt * 16;
#pragma unroll
        for (int kt = 0; kt < 2; ++kt) {
            const int kb = kt * 32 + q * 8;
            bf16x8 fi, fh;
#pragma unroll
            for (int j = 0; j < 8; ++j) {
                const int k = kb + j;
                float vi = (k < ldih) ? Wih[(gc + n_) * ldih + k] : 0.0f;
                fi[j] = f2bf(vi);
                fh[j] = f2bf(Whh[(gc + n_) * 64 + k]);
            }
            wihf[g][kt] = fi;
            whhf[g][kt] = fh;
        }
    }

    // bias C-init vectors (C col = l&15; same bias for all 4 row-regs)
    f32x4 cinit_r, cinit_z, cinit_xn, cinit_hn;
    {
        const int c0 = qt * 16 + n_;
        float br = bih[c0] + bhh[c0];
        float bz = bih[64 + c0] + bhh[64 + c0];
        float bx = bih[128 + c0];
        float bh = bhh[128 + c0];
        cinit_r  = (f32x4){br, br, br, br};
        cinit_z  = (f32x4){bz, bz, bz, bz};
        cinit_xn = (f32x4){bx, bx, bx, bx};
        cinit_hn = (f32x4){bh, bh, bh, bh};
    }

    float hp = 0.0f;

    // input/own A-frag pipeline regs. Lanes never written by the masked
    // loads below keep these zeros forever (no NaN from stale regs).
    bf16x8 iA0 = {0,0,0,0,0,0,0,0}, iA1 = {0,0,0,0,0,0,0,0};
    bf16x8 hA0 = {0,0,0,0,0,0,0,0}, hA1 = {0,0,0,0,0,0,0,0};
    f32x4 xfa = {0.f,0.f,0.f,0.f}, xfb = {0.f,0.f,0.f,0.f};
    const float* xlane = nullptr;
    if (L == 0) {
        int row = rbase + n_;
        if (row > 1023) row = 1023;           // clamp (rows >=4 feed discarded C rows)
        xlane = x + (long)row * (TT * 16) + q * 8;
        if (q < 2) {                          // k = q*8+j < 16 real; q>=2 stays zero
            xfa = *(const f32x4*)(xlane);
            xfb = *(const f32x4*)(xlane + 4);
        }
        iA0 = packx(xfa, xfb);                // x(0)
        if (q < 2) {                          // start pipeline: x(1) in flight
            xfa = *(const f32x4*)(xlane + 16);
            xfb = *(const f32x4*)(xlane + 16 + 4);
        }
    }
    __syncthreads();

    for (int s = 0; s < TT + 4; ++s) {
        const int tw = s - 2 * L;
        if ((unsigned)tw < TT) {
            // own-h frags h_L(tw-1): slot (tw-1) mod 3 == (tw+2)%3 (zeros at tw=0)
            const short* own = &hbuf[L][(tw + 2) % 3][0];
            if (n_ < 4) {
                hA0 = *(const bf16x8*)(own + n_ * 96 + q * 8);
                hA1 = *(const bf16x8*)(own + n_ * 96 + 32 + q * 8);
            }
            // ih MFMAs first (iA prefetched last step -> no wait)
            f32x4 cr, cz, cxn, chn;
            cr  = MFMA(iA0, wihf[0][0], cinit_r);
            cz  = MFMA(iA0, wihf[1][0], cinit_z);
            cxn = MFMA(iA0, wihf[2][0], cinit_xn);
            if (L != 0) {                      // L0's k=32..63 ih tile is all-zero
                cr  = MFMA(iA1, wihf[0][1], cr);
                cz  = MFMA(iA1, wihf[1][1], cz);
                cxn = MFMA(iA1, wihf[2][1], cxn);
            }
            cr  = MFMA(hA0, whhf[0][0], cr);
            cr  = MFMA(hA1, whhf[0][1], cr);
            cz  = MFMA(hA0, whhf[1][0], cz);
            cz  = MFMA(hA1, whhf[1][1], cz);
            chn = MFMA(hA0, whhf[2][0], cinit_hn);
            chn = MFMA(hA1, whhf[2][1], chn);

            // redistribute preacts (biases already baked in) and gate
            float pr  = sel4bp(bpa, cr,  grow);
            float pz  = sel4bp(bpa, cz,  grow);
            float pxn = sel4bp(bpa, cxn, grow);
            float phn = sel4bp(bpa, chn, grow);
            float rr = sigm(pr);
            float zz = sigm(pz);
            float nn = tanh_(pxn + rr * phn);
            float hv = nn + zz * (hp - nn);
            hp = hv;
            hbuf[L][tw % 3][grow * 96 + u] = f2bf(hv);
        }
        // prefetch inp frag for t+1 (producer wrote it at step s-1: barrier-ordered)
        const int tn = tw + 1;
        if ((unsigned)tn < TT) {
            if (L == 0) {
                iA0 = packx(xfa, xfb);         // x(tn)
                const int tl = (tn + 1 < TT) ? tn + 1 : tn;
                if (q < 2) {
                    xfa = *(const f32x4*)(xlane + tl * 16);
                    xfb = *(const f32x4*)(xlane + tl * 16 + 4);
                }
            } else {
                const short* inp = &hbuf[L - 1][tn % 3][0];
                if (n_ < 4) {
                    iA0 = *(const bf16x8*)(inp + n_ * 96 + q * 8);
                    iA1 = *(const bf16x8*)(inp + n_ * 96 + 32 + q * 8);
                }
            }
        }
        __syncthreads();
    }

    // FC head: L2 waves hold h2(T-1), one value per lane
    if (wid >= 8) h2out[grow][u] = hp;
    __syncthreads();
    if (tid < 128) {
        const int row = tid >> 5, uu = tid & 31;
        float acc = fc1b[uu];
#pragma unroll
        for (int k = 0; k < 64; ++k) acc += h2out[row][k] * fc1w[uu * 64 + k];
        fcz[row][uu] = fmaxf(acc, 0.0f);
    }
    __syncthreads();
    if (tid < 4) {
        float y = fc2b[0];
#pragma unroll
        for (int uu = 0; uu < 32; ++uu) y += fcz[tid][uu] * fc2w[uu];
        out[rbase + tid] = y;
    }
}

extern "C" void kernel_launch(void* const* d_in, const int* in_sizes, int n_in,
                              void* d_out, int out_size, void* d_ws, size_t ws_size,
                              hipStream_t stream) {
    (void)in_sizes; (void)n_in; (void)d_ws; (void)ws_size; (void)out_size;
    gru_fused<<<dim3(256), dim3(768), 0, stream>>>(
        (const float*)d_in[0],
        (const float*)d_in[1],  (const float*)d_in[2],  (const float*)d_in[3],  (const float*)d_in[4],
        (const float*)d_in[5],  (const float*)d_in[6],  (const float*)d_in[7],  (const float*)d_in[8],
        (const float*)d_in[9],  (const float*)d_in[10], (const float*)d_in[11], (const float*)d_in[12],
        (const float*)d_in[13], (const float*)d_in[14], (const float*)d_in[15], (const float*)d_in[16],
        (float*)d_out);
}

// Round 5
// 557.368 us; speedup vs baseline: 1.1266x; 1.1266x over previous
//
#include <hip/hip_runtime.h>

#define TT 512

typedef __attribute__((ext_vector_type(8))) short bf16x8;
typedef __attribute__((ext_vector_type(4))) float f32x4;

__device__ inline short f2bf(float f) {
    // round-to-nearest-even fp32 -> bf16
    unsigned u = __float_as_uint(f);
    u += 0x7FFFu + ((u >> 16) & 1u);
    return (short)(u >> 16);
}
__device__ inline float sigm(float x)  { return __fdividef(1.0f, 1.0f + __expf(-x)); }
__device__ inline float tanh_(float x) { return 1.0f - __fdividef(2.0f, 1.0f + __expf(2.0f * x)); }

#define MFMA(A, B, C) __builtin_amdgcn_mfma_f32_16x16x32_bf16((A), (B), (C), 0, 0, 0)

// 768 threads = 12 waves = 3 layers x 4 unit-quarters; WG owns 4 batch rows,
// grid=256 = 1 WG/CU. Layer pipeline skewed by 2 (wave L does t = s-2L): the
// producer's h is 2 barriers old, so inp A-frags are prefetched one step early
// (off the critical path). Preact redistribution via conflict-free LDS
// scatter(16 lanes)/gather (stride-6 pad). x staged by wave0 through a 3-slot
// LDS ring fed by a 2-register global prefetch pipeline.
// R4 fix: A-frag loads need the per-quad k-offset (+ q*8) — R3 dropped it.
__global__ __launch_bounds__(768, 1)
void gru_fused(const float* __restrict__ x,
               const float* __restrict__ Wih0, const float* __restrict__ Whh0,
               const float* __restrict__ bih0, const float* __restrict__ bhh0,
               const float* __restrict__ Wih1, const float* __restrict__ Whh1,
               const float* __restrict__ bih1, const float* __restrict__ bhh1,
               const float* __restrict__ Wih2, const float* __restrict__ Whh2,
               const float* __restrict__ bih2, const float* __restrict__ bhh2,
               const float* __restrict__ fc1w, const float* __restrict__ fc1b,
               const float* __restrict__ fc2w, const float* __restrict__ fc2b,
               float* __restrict__ out)
{
    // h ring: [layer][t%3][row 0..3][96 shorts]; 192B row stride -> 16B-aligned frags
    __shared__ __align__(16) short hbuf[3][3][4 * 96];
    __shared__ __align__(16) short xbuf[3][4 * 96];
    // per-wave preact scratch, stride 6 floats: write banks 6n_%32 all-distinct,
    // read banks (6c+r)%32 <=3-way
    __shared__ float pre[12][4][16][6];
    __shared__ float h2out[4][64];
    __shared__ float fcz[4][32];

    const int tid = threadIdx.x;
    const int l   = tid & 63;
    const int wid = tid >> 6;   // 0..11
    const int L   = wid >> 2;   // layer
    const int qt  = wid & 3;    // unit quarter
    const int n_  = l & 15;     // A row / B col / C col
    const int q   = l >> 4;     // quad
    const int rbase = blockIdx.x * 4;
    const int grow = l >> 4;    // gate: batch row
    const int gcol = l & 15;    // gate: col within quarter
    const int u    = qt * 16 + gcol;

    for (int i = tid; i < 3 * 3 * 4 * 96; i += 768) (&hbuf[0][0][0])[i] = 0;
    for (int i = tid; i < 3 * 4 * 96; i += 768) (&xbuf[0][0])[i] = 0;
    __syncthreads();

    // ---- wave0: x stage pipeline (rows rbase..rbase+3, k=0..15; one val/lane) ----
    float xr_a = 0.0f, xr_b = 0.0f;
    const float* xg = nullptr;
    if (wid == 0) {
        xg = x + ((long)(rbase + (l >> 4)) * TT) * 16 + (l & 15);
        xbuf[0][(l >> 4) * 96 + (l & 15)] = f2bf(xg[0]);
        xbuf[1][(l >> 4) * 96 + (l & 15)] = f2bf(xg[16]);
        xr_a = xg[2 * 16];   // x(2), written at s=0
        xr_b = xg[3 * 16];   // x(3), written at s=1
    }

    const float* Wih = (L == 0) ? Wih0 : (L == 1) ? Wih1 : Wih2;
    const float* Whh = (L == 0) ? Whh0 : (L == 1) ? Whh1 : Whh2;
    const float* bih = (L == 0) ? bih0 : (L == 1) ? bih1 : bih2;
    const float* bhh = (L == 0) ? bhh0 : (L == 1) ? bhh1 : bhh2;
    const int ldih = (L == 0) ? 16 : 64;

    // resident B-frags (gate g: 0=r,1=z,2=n; cols g*64+qt*16..+15; k=kt*32+q*8+j)
    bf16x8 wihf[3][2], whhf[3][2];
#pragma unroll
    for (int g = 0; g < 3; ++g) {
        const int gc = g * 64 + qt * 16;
#pragma unroll
        for (int kt = 0; kt < 2; ++kt) {
            const int kb = kt * 32 + q * 8;
            bf16x8 fi, fh;
#pragma unroll
            for (int j = 0; j < 8; ++j) {
                const int k = kb + j;
                float vi = (k < ldih) ? Wih[(gc + n_) * ldih + k] : 0.0f;
                fi[j] = f2bf(vi);
                fh[j] = f2bf(Whh[(gc + n_) * 64 + k]);
            }
            wihf[g][kt] = fi;
            whhf[g][kt] = fh;
        }
    }

    // bias C-init vectors (C col = n_; same bias for all 4 row-regs)
    f32x4 cinit_r, cinit_z, cinit_xn, cinit_hn;
    {
        const int c0 = qt * 16 + n_;
        float br = bih[c0] + bhh[c0];
        float bz = bih[64 + c0] + bhh[64 + c0];
        float bx = bih[128 + c0];
        float bh = bhh[128 + c0];
        cinit_r  = (f32x4){br, br, br, br};
        cinit_z  = (f32x4){bz, bz, bz, bz};
        cinit_xn = (f32x4){bx, bx, bx, bx};
        cinit_hn = (f32x4){bh, bh, bh, bh};
    }

    float hp = 0.0f;
    // A-frag pipeline regs; unwritten lanes keep zeros forever (no NaN risk)
    bf16x8 iA0 = {0,0,0,0,0,0,0,0}, iA1 = {0,0,0,0,0,0,0,0};
    bf16x8 hA0 = {0,0,0,0,0,0,0,0}, hA1 = {0,0,0,0,0,0,0,0};

    __syncthreads();
    // L0 waves preload iA0 for t=0 (xbuf[0] written before the barrier above)
    if (L == 0 && n_ < 4) iA0 = *(const bf16x8*)(&xbuf[0][n_ * 96 + q * 8]);

    for (int s = 0; s < TT + 4; ++s) {
        const int tw = s - 2 * L;
        const bool docomp = (unsigned)tw < TT;
        const bool dopref = (unsigned)(tw + 1) < TT;

        f32x4 cr, cz, cxn, chn;
        if (docomp) {
            // own-h h_L(tw-1): slot (tw-1)%3 == (tw+2)%3; zeros at tw==0
            const short* own = &hbuf[L][(tw + 2) % 3][0];
            if (n_ < 4) {
                hA0 = *(const bf16x8*)(own + n_ * 96 + q * 8);
                hA1 = *(const bf16x8*)(own + n_ * 96 + 32 + q * 8);
            }
            cr  = MFMA(iA0, wihf[0][0], cinit_r);
            cz  = MFMA(iA0, wihf[1][0], cinit_z);
            cxn = MFMA(iA0, wihf[2][0], cinit_xn);
            if (L != 0) {                    // L0's k=32..63 ih tile is all-zero
                cr  = MFMA(iA1, wihf[0][1], cr);
                cz  = MFMA(iA1, wihf[1][1], cz);
                cxn = MFMA(iA1, wihf[2][1], cxn);
            }
            cr  = MFMA(hA0, whhf[0][0], cr);
            cr  = MFMA(hA1, whhf[0][1], cr);
            cz  = MFMA(hA0, whhf[1][0], cz);
            cz  = MFMA(hA1, whhf[1][1], cz);
            chn = MFMA(hA0, whhf[2][0], cinit_hn);
            chn = MFMA(hA1, whhf[2][1], chn);
        }
        // prefetch inp frag for t+1 (producer wrote it one barrier ago)
        if (dopref) {
            const int tn = tw + 1;
            if (L == 0) {
                if (n_ < 4) iA0 = *(const bf16x8*)(&xbuf[tn % 3][n_ * 96 + q * 8]);
            } else {
                const short* inp = &hbuf[L - 1][tn % 3][0];
                if (n_ < 4) {
                    iA0 = *(const bf16x8*)(inp + n_ * 96 + q * 8);
                    iA1 = *(const bf16x8*)(inp + n_ * 96 + 32 + q * 8);
                }
            }
        }
        if (docomp) {
            // scatter valid C rows (q==0 lanes hold rows 0..3) -- conflict-free
            if (q == 0) {
#pragma unroll
                for (int r = 0; r < 4; ++r) {
                    pre[wid][0][n_][r] = cr[r];
                    pre[wid][1][n_][r] = cz[r];
                    pre[wid][2][n_][r] = cxn[r];
                    pre[wid][3][n_][r] = chn[r];
                }
            }
            // gather: one h-unit per lane (biases already baked into C)
            const float pr  = pre[wid][0][gcol][grow];
            const float pz  = pre[wid][1][gcol][grow];
            const float pxn = pre[wid][2][gcol][grow];
            const float phn = pre[wid][3][gcol][grow];
            const float rr = sigm(pr);
            const float zz = sigm(pz);
            const float nn = tanh_(pxn + rr * phn);
            const float hv = nn + zz * (hp - nn);
            hp = hv;
            hbuf[L][tw % 3][grow * 96 + u] = f2bf(hv);
        }
        // wave0: stage x(s+2) from the register pipeline; load x(s+4)
        if (wid == 0) {
            const int ts = s + 2;
            if (ts < TT) xbuf[ts % 3][(l >> 4) * 96 + (l & 15)] = f2bf(xr_a);
            xr_a = xr_b;
            int tl = s + 4; if (tl > TT - 1) tl = TT - 1;
            xr_b = xg[tl * 16];
        }
        __syncthreads();
    }

    // FC head: L2 waves hold h2(T-1), one value per lane
    if (wid >= 8) h2out[grow][u] = hp;
    __syncthreads();
    if (tid < 128) {
        const int row = tid >> 5, uu = tid & 31;
        float acc = fc1b[uu];
#pragma unroll
        for (int k = 0; k < 64; ++k) acc += h2out[row][k] * fc1w[uu * 64 + k];
        fcz[row][uu] = fmaxf(acc, 0.0f);
    }
    __syncthreads();
    if (tid < 4) {
        float y = fc2b[0];
#pragma unroll
        for (int uu = 0; uu < 32; ++uu) y += fcz[tid][uu] * fc2w[uu];
        out[rbase + tid] = y;
    }
}

extern "C" void kernel_launch(void* const* d_in, const int* in_sizes, int n_in,
                              void* d_out, int out_size, void* d_ws, size_t ws_size,
                              hipStream_t stream) {
    (void)in_sizes; (void)n_in; (void)d_ws; (void)ws_size; (void)out_size;
    gru_fused<<<dim3(256), dim3(768), 0, stream>>>(
        (const float*)d_in[0],
        (const float*)d_in[1],  (const float*)d_in[2],  (const float*)d_in[3],  (const float*)d_in[4],
        (const float*)d_in[5],  (const float*)d_in[6],  (const float*)d_in[7],  (const float*)d_in[8],
        (const float*)d_in[9],  (const float*)d_in[10], (const float*)d_in[11], (const float*)d_in[12],
        (const float*)d_in[13], (const float*)d_in[14], (const float*)d_in[15], (const float*)d_in[16],
        (float*)d_out);
}

// Round 6
// 555.125 us; speedup vs baseline: 1.1311x; 1.0040x over previous
//
#include <hip/hip_runtime.h>

#define TT 512

typedef __attribute__((ext_vector_type(8))) short bf16x8;
typedef __attribute__((ext_vector_type(4))) float f32x4;

__device__ inline short f2bf(float f) {
    // round-to-nearest-even fp32 -> bf16
    unsigned u = __float_as_uint(f);
    u += 0x7FFFu + ((u >> 16) & 1u);
    return (short)(u >> 16);
}
__device__ inline float sigm(float x)  { return __fdividef(1.0f, 1.0f + __expf(-x)); }
__device__ inline float tanh_(float x) { return 1.0f - __fdividef(2.0f, 1.0f + __expf(2.0f * x)); }

#define MFMA(A, B, C) __builtin_amdgcn_mfma_f32_16x16x32_bf16((A), (B), (C), 0, 0, 0)

// 768 threads = 12 waves = 3 layers x 4 unit-quarters; WG owns 4 batch rows,
// grid=256 = 1 WG/CU. Skew-2 layer pipeline (wave L does t = s-2L), inp frags
// prefetched one step early. R5 changes (R4 post-mortem: per-CU LDS pipe
// ~1340cy/step + exposed global-load latency + ring-address VALU dominate):
//   - b128 scatter (pre[...][4] layout, 2-way banks = free) : 16 b32 -> 4 b128
//   - time loop unrolled x4 over a 4-slot ring: slot math compile-time,
//     all LDS lane addresses hoisted to registers
//   - wave-uniform control scalarized via readfirstlane (SALU branches)
//   - x loads batched 4/iter at iteration TOP so the vmcnt(0) barrier drain
//     sees ~1-step-old loads (m97: __syncthreads drains vmcnt(0))
__global__ __launch_bounds__(768, 1)
void gru_fused(const float* __restrict__ x,
               const float* __restrict__ Wih0, const float* __restrict__ Whh0,
               const float* __restrict__ bih0, const float* __restrict__ bhh0,
               const float* __restrict__ Wih1, const float* __restrict__ Whh1,
               const float* __restrict__ bih1, const float* __restrict__ bhh1,
               const float* __restrict__ Wih2, const float* __restrict__ Whh2,
               const float* __restrict__ bih2, const float* __restrict__ bhh2,
               const float* __restrict__ fc1w, const float* __restrict__ fc1b,
               const float* __restrict__ fc2w, const float* __restrict__ fc2b,
               float* __restrict__ out)
{
    // h ring: [layer][t&3][row 0..3][96 shorts]; 192B rows -> 16B-aligned frags
    __shared__ __align__(16) short hbuf[3][4][4 * 96];
    __shared__ __align__(16) short xbuf[4][4 * 96];
    // per-wave preact scratch [gate][col][row4]: b128 scatter (banks 4n_%32,
    // 2-way = free), b32 gather (banks (4c+r)%32, 2-way = free)
    __shared__ __align__(16) float pre[12][4][16][4];
    __shared__ float h2out[4][64];
    __shared__ float fcz[4][32];

    const int tid = threadIdx.x;
    const int l   = tid & 63;
    const int wid = tid >> 6;   // 0..11
    const int L   = wid >> 2;   // layer
    const int qt  = wid & 3;    // unit quarter
    const int n_  = l & 15;     // A row / B col / C col
    const int q   = l >> 4;     // quad
    const int rbase = blockIdx.x * 4;
    const int grow = l >> 4;    // gate: batch row
    const int gcol = l & 15;    // gate: col within quarter
    const int u    = qt * 16 + gcol;

    // wave-uniform scalars -> SALU control flow
    const int wids = __builtin_amdgcn_readfirstlane(wid);
    const int Ls   = wids >> 2;

    for (int i = tid; i < 3 * 4 * 4 * 96; i += 768) (&hbuf[0][0][0])[i] = 0;
    for (int i = tid; i < 4 * 4 * 96; i += 768) (&xbuf[0][0])[i] = 0;
    __syncthreads();

    // ---- wave0: x staging. 4-deep register pipeline, loads issued at iter top ----
    float xr0 = 0.f, xr1 = 0.f, xr2 = 0.f, xr3 = 0.f;
    float xn0 = 0.f, xn1 = 0.f, xn2 = 0.f, xn3 = 0.f;
    const float* xg = nullptr;
    if (wids == 0) {
        xg = x + ((long)(rbase + grow) * TT) * 16 + gcol;
        xbuf[0][grow * 96 + gcol] = f2bf(xg[0]);
        xbuf[1][grow * 96 + gcol] = f2bf(xg[16]);
        xr0 = xg[2 * 16]; xr1 = xg[3 * 16]; xr2 = xg[4 * 16]; xr3 = xg[5 * 16];
    }

    const float* Wih = (L == 0) ? Wih0 : (L == 1) ? Wih1 : Wih2;
    const float* Whh = (L == 0) ? Whh0 : (L == 1) ? Whh1 : Whh2;
    const float* bih = (L == 0) ? bih0 : (L == 1) ? bih1 : bih2;
    const float* bhh = (L == 0) ? bhh0 : (L == 1) ? bhh1 : bhh2;
    const int ldih = (L == 0) ? 16 : 64;

    // resident B-frags (gate g: 0=r,1=z,2=n; cols g*64+qt*16..+15; k=kt*32+q*8+j)
    bf16x8 wihf[3][2], whhf[3][2];
#pragma unroll
    for (int g = 0; g < 3; ++g) {
        const int gc = g * 64 + qt * 16;
#pragma unroll
        for (int kt = 0; kt < 2; ++kt) {
            const int kb = kt * 32 + q * 8;
            bf16x8 fi, fh;
#pragma unroll
            for (int j = 0; j < 8; ++j) {
                const int k = kb + j;
                float vi = (k < ldih) ? Wih[(gc + n_) * ldih + k] : 0.0f;
                fi[j] = f2bf(vi);
                fh[j] = f2bf(Whh[(gc + n_) * 64 + k]);
            }
            wihf[g][kt] = fi;
            whhf[g][kt] = fh;
        }
    }

    // bias C-init vectors
    f32x4 cinit_r, cinit_z, cinit_xn, cinit_hn;
    {
        const int c0 = qt * 16 + n_;
        float br = bih[c0] + bhh[c0];
        float bz = bih[64 + c0] + bhh[64 + c0];
        float bx = bih[128 + c0];
        float bh = bhh[128 + c0];
        cinit_r  = (f32x4){br, br, br, br};
        cinit_z  = (f32x4){bz, bz, bz, bz};
        cinit_xn = (f32x4){bx, bx, bx, bx};
        cinit_hn = (f32x4){bh, bh, bh, bh};
    }

    float hp = 0.0f;
    bf16x8 iA0 = {0,0,0,0,0,0,0,0}, iA1 = {0,0,0,0,0,0,0,0};
    bf16x8 hA0 = {0,0,0,0,0,0,0,0}, hA1 = {0,0,0,0,0,0,0,0};

    // hoisted per-substep LDS lane pointers (slots loop-invariant after x4 unroll)
    const short* ownp[4]; const short* inpp[4]; short* hwp[4];
#pragma unroll
    for (int ss = 0; ss < 4; ++ss) {
        const int so = (ss - 2 * Ls + 7) & 3;   // slot of tw-1 (own h)
        const int si = (ss - 2 * Ls + 9) & 3;   // slot of tw+1 (inp prefetch)
        const int sw = (ss - 2 * Ls + 8) & 3;   // slot of tw   (h write)
        ownp[ss] = &hbuf[Ls][so][0] + n_ * 96 + q * 8;
        inpp[ss] = (Ls == 0) ? &xbuf[si][0] + n_ * 96 + q * 8
                             : &hbuf[Ls - 1][si][0] + n_ * 96 + q * 8;
        hwp[ss]  = &hbuf[Ls][sw][0] + grow * 96 + u;
    }
    float*       prew = &pre[wid][0][n_][0];     // scatter base (q==0 lanes)
    const float* preg = &pre[wid][0][gcol][grow]; // gather base (+g*64)

    __syncthreads();
    if (Ls == 0 && n_ < 4) iA0 = *(const bf16x8*)(&xbuf[0][n_ * 96 + q * 8]);

    for (int s0 = 0; s0 < TT + 4; s0 += 4) {
        // issue next 4 x loads at iter TOP (drained by this iter's barriers,
        // ~1 step old by the first drain -> latency hidden)
        if (wids == 0) {
            int i0 = s0 + 6; if (i0 > TT - 1) i0 = TT - 1;
            int i1 = s0 + 7; if (i1 > TT - 1) i1 = TT - 1;
            int i2 = s0 + 8; if (i2 > TT - 1) i2 = TT - 1;
            int i3 = s0 + 9; if (i3 > TT - 1) i3 = TT - 1;
            xn0 = xg[i0 * 16]; xn1 = xg[i1 * 16];
            xn2 = xg[i2 * 16]; xn3 = xg[i3 * 16];
        }
#pragma unroll
        for (int ss = 0; ss < 4; ++ss) {
            const int s  = s0 + ss;
            const int tw = s - 2 * Ls;
            const bool docomp = (unsigned)tw < TT;
            f32x4 cr, cz, cxn, chn;
            if (docomp) {
                if (n_ < 4) {
                    hA0 = *(const bf16x8*)(ownp[ss]);
                    hA1 = *(const bf16x8*)(ownp[ss] + 32);
                }
                cr  = MFMA(iA0, wihf[0][0], cinit_r);
                cz  = MFMA(iA0, wihf[1][0], cinit_z);
                cxn = MFMA(iA0, wihf[2][0], cinit_xn);
                if (Ls != 0) {                  // L0's k=32..63 ih tile is all-zero
                    cr  = MFMA(iA1, wihf[0][1], cr);
                    cz  = MFMA(iA1, wihf[1][1], cz);
                    cxn = MFMA(iA1, wihf[2][1], cxn);
                }
                cr  = MFMA(hA0, whhf[0][0], cr);
                cr  = MFMA(hA1, whhf[0][1], cr);
                cz  = MFMA(hA0, whhf[1][0], cz);
                cz  = MFMA(hA1, whhf[1][1], cz);
                chn = MFMA(hA0, whhf[2][0], cinit_hn);
                chn = MFMA(hA1, whhf[2][1], chn);
            }
            // prefetch inp frag for t+1 (producer wrote it one barrier ago)
            if ((unsigned)(tw + 1) < TT) {
                if (Ls == 0) {
                    if (n_ < 4) iA0 = *(const bf16x8*)(inpp[ss]);
                } else if (n_ < 4) {
                    iA0 = *(const bf16x8*)(inpp[ss]);
                    iA1 = *(const bf16x8*)(inpp[ss] + 32);
                }
            }
            if (docomp) {
                if (q == 0) {                    // b128 scatter, 2-way banks (free)
                    *(f32x4*)(prew)       = cr;
                    *(f32x4*)(prew + 64)  = cz;
                    *(f32x4*)(prew + 128) = cxn;
                    *(f32x4*)(prew + 192) = chn;
                }
                const float pr  = preg[0];       // b32 gather, 2-way banks (free)
                const float pz  = preg[64];
                const float pxn = preg[128];
                const float phn = preg[192];
                const float rr = sigm(pr);
                const float zz = sigm(pz);
                const float nn = tanh_(pxn + rr * phn);
                const float hv = nn + zz * (hp - nn);
                hp = hv;
                *hwp[ss] = f2bf(hv);
            }
            if (wids == 0 && s + 2 < TT) {
                float xv = (ss == 0) ? xr0 : (ss == 1) ? xr1 : (ss == 2) ? xr2 : xr3;
                xbuf[(ss + 2) & 3][grow * 96 + gcol] = f2bf(xv);
            }
            __syncthreads();
        }
        if (wids == 0) { xr0 = xn0; xr1 = xn1; xr2 = xn2; xr3 = xn3; }
    }

    // FC head: L2 waves hold h2(T-1), one value per lane
    if (Ls == 2) h2out[grow][u] = hp;
    __syncthreads();
    if (tid < 128) {
        const int row = tid >> 5, uu = tid & 31;
        float acc = fc1b[uu];
#pragma unroll
        for (int k = 0; k < 64; ++k) acc += h2out[row][k] * fc1w[uu * 64 + k];
        fcz[row][uu] = fmaxf(acc, 0.0f);
    }
    __syncthreads();
    if (tid < 4) {
        float y = fc2b[0];
#pragma unroll
        for (int uu = 0; uu < 32; ++uu) y += fcz[tid][uu] * fc2w[uu];
        out[rbase + tid] = y;
    }
}

extern "C" void kernel_launch(void* const* d_in, const int* in_sizes, int n_in,
                              void* d_out, int out_size, void* d_ws, size_t ws_size,
                              hipStream_t stream) {
    (void)in_sizes; (void)n_in; (void)d_ws; (void)ws_size; (void)out_size;
    gru_fused<<<dim3(256), dim3(768), 0, stream>>>(
        (const float*)d_in[0],
        (const float*)d_in[1],  (const float*)d_in[2],  (const float*)d_in[3],  (const float*)d_in[4],
        (const float*)d_in[5],  (const float*)d_in[6],  (const float*)d_in[7],  (const float*)d_in[8],
        (const float*)d_in[9],  (const float*)d_in[10], (const float*)d_in[11], (const float*)d_in[12],
        (const float*)d_in[13], (const float*)d_in[14], (const float*)d_in[15], (const float*)d_in[16],
        (float*)d_out);
}